// Round 6
// baseline (909.407 us; speedup 1.0000x reference)
//
#include <hip/hip_runtime.h>
#include <hip/hip_bf16.h>
#include <hip/hip_fp16.h>

typedef float f32x4 __attribute__((ext_vector_type(4)));
typedef short s16x8 __attribute__((ext_vector_type(8)));
typedef unsigned short u16;

#define LOG2F 0.6931471805599453f
#define LDA 136   // padded LDS row stride (bf16 elems): 2-way bank alias only (free)
#define BNG 512   // bnmid grid (also its partial count)

__device__ __forceinline__ u16 f2bf(float f) {               // RNE f32->bf16
  unsigned u = __float_as_uint(f);
  u += 0x7fffu + ((u >> 16) & 1u);
  return (u16)(u >> 16);
}
__device__ __forceinline__ float bf2f(u16 h){ return __uint_as_float((unsigned)h << 16); }
__device__ __forceinline__ float bflo(unsigned u){ return __uint_as_float(u << 16); }
__device__ __forceinline__ float bfhi(unsigned u){ return __uint_as_float(u & 0xffff0000u); }
__device__ __forceinline__ u16 f2h(float f){ __half h = __float2half(f); return __half_as_ushort(h); }

// packed f16: relu(a+b) then dot2-accumulate (CDNA VOP3P deep-learning ops)
__device__ __forceinline__ unsigned pk_add_relu(unsigned a, unsigned b){
  unsigned t, r;
  asm("v_pk_add_f16 %0, %1, %2" : "=v"(t) : "v"(a), "v"(b));
  asm("v_pk_max_f16 %0, %1, 0" : "=v"(r) : "v"(t));
  return r;
}
__device__ __forceinline__ float dot2acc(unsigned a, unsigned w, float c){
  asm("v_dot2_f32_f16 %0, %1, %2, %0" : "+v"(c) : "v"(a), "v"(w));
  return c;
}
// fast softplus(-s) = max(-s,0) + log(1+exp(-|s|)) via hw exp2/log2
// (v_exp_f32 = 2^x, v_log_f32 = log2(x))
__device__ __forceinline__ float softplus_neg(float s){
  float e = __builtin_amdgcn_exp2f(-fabsf(s) * 1.442695040888963f);
  return fmaxf(-s, 0.f) + __builtin_amdgcn_logf(1.f + e) * 0.6931471805599453f;
}

// ---- convert+transpose weights to bf16: Wt[m][c][k] = W_m[k][c] ----
__global__ void convw(const float* __restrict__ gW, const float* __restrict__ Wlin,
                      u16* __restrict__ Wt, int L) {
  int idx = blockIdx.x * 256 + threadIdx.x;
  int total = (L + 2) * 16384;
  if (idx >= total) return;
  int m = idx >> 14, rem = idx & 16383, c = rem >> 7, k = rem & 127;
  float v;
  if (m < L)           v = gW[(size_t)m * 16384 + k * 128 + c];
  else if (m == L)     v = Wlin[k * 128 + c];            // top half (root)
  else                 v = Wlin[(128 + k) * 128 + c];    // bottom half (features)
  Wt[idx] = f2bf(v);
}

// Wu f32 -> f16
__global__ void convu(const float* __restrict__ Wu, u16* __restrict__ wuh) {
  wuh[threadIdx.x] = f2h(Wu[threadIdx.x]);
}

// features f32 -> bf16
__global__ void convf(const float* __restrict__ in, u16* __restrict__ out, int n4) {
  int stride = gridDim.x * blockDim.x;
  for (int i = blockIdx.x * blockDim.x + threadIdx.x; i < n4; i += stride) {
    float4 v = ((const float4*)in)[i];
    ushort4 o; o.x = f2bf(v.x); o.y = f2bf(v.y); o.z = f2bf(v.z); o.w = f2bf(v.w);
    ((ushort4*)out)[i] = o;
  }
}

// ---------------- CSR build (dst -> list of src), deterministic ----------------
__global__ void cntk(int* __restrict__ cnt, const int* __restrict__ edst, int E) {
  int e = blockIdx.x * 256 + threadIdx.x;
  if (e < E) atomicAdd(&cnt[edst[e]], 1);
}

__global__ void scanA(const int* __restrict__ cnt, int* __restrict__ excl,
                      int* __restrict__ bsum, int N) {
  __shared__ int tmp[256];
  int i = blockIdx.x * 256 + threadIdx.x;
  int v = (i < N) ? cnt[i] : 0;
  tmp[threadIdx.x] = v;
  __syncthreads();
  for (int off = 1; off < 256; off <<= 1) {
    int t = (threadIdx.x >= off) ? tmp[threadIdx.x - off] : 0;
    __syncthreads();
    tmp[threadIdx.x] += t;
    __syncthreads();
  }
  if (i < N) excl[i] = tmp[threadIdx.x] - v;
  if (threadIdx.x == 255) bsum[blockIdx.x] = tmp[255];
}

__global__ void scanB(const int* __restrict__ bsum, int* __restrict__ boff,
                      int nb, int* __restrict__ rowptrN) {
  __shared__ int tmp[256];
  __shared__ int carry;
  if (threadIdx.x == 0) carry = 0;
  __syncthreads();
  for (int base = 0; base < nb; base += 256) {
    int i = base + threadIdx.x;
    int v = (i < nb) ? bsum[i] : 0;
    tmp[threadIdx.x] = v;
    __syncthreads();
    for (int off = 1; off < 256; off <<= 1) {
      int t = (threadIdx.x >= off) ? tmp[threadIdx.x - off] : 0;
      __syncthreads();
      tmp[threadIdx.x] += t;
      __syncthreads();
    }
    if (i < nb) boff[i] = carry + tmp[threadIdx.x] - v;
    __syncthreads();
    if (threadIdx.x == 255) carry += tmp[255];
    __syncthreads();
  }
  if (threadIdx.x == 0) *rowptrN = carry;
}

__global__ void scanC(const int* __restrict__ excl, const int* __restrict__ boff,
                      int* __restrict__ rowptr, int* __restrict__ cursor, int N) {
  int i = blockIdx.x * 256 + threadIdx.x;
  if (i < N) {
    int r = excl[i] + boff[blockIdx.x];
    rowptr[i] = r; cursor[i] = r;
  }
}

__global__ void fillk(const int* __restrict__ esrc, const int* __restrict__ edst,
                      int* __restrict__ cursor, int* __restrict__ col, int E) {
  int e = blockIdx.x * 256 + threadIdx.x;
  if (e < E) {
    int pos = atomicAdd(&cursor[edst[e]], 1);
    col[pos] = esrc[e];
  }
}

// per-node insertion sort of CSR sublist -> deterministic gather order
__global__ void sortk(const int* __restrict__ rowptr, int* __restrict__ col, int N) {
  int n = blockIdx.x * 256 + threadIdx.x;
  if (n >= N) return;
  int lo = rowptr[n], hi = rowptr[n + 1];
  for (int i = lo + 1; i < hi; i++) {
    int v = col[i];
    int j = i - 1;
    while (j >= lo && col[j] > v) { col[j + 1] = col[j]; j--; }
    col[j + 1] = v;
  }
}

// ---------------- GIN aggregation: out[n] = bf16((1+eps)*emb[n] + sum_src emb[src]) ----------------
// 2 nodes per wave (32 lanes x uint2 per row) for extra MLP
__global__ __launch_bounds__(256) void aggk0(
    const u16* __restrict__ emb, u16* __restrict__ out,
    const int* __restrict__ rowptr, const int* __restrict__ col,
    const float* __restrict__ epsp, int l, int N) {
  int tid = threadIdx.x;
  int wave = tid >> 6, lane = tid & 63;
  int n = blockIdx.x * 8 + wave * 2 + (lane >> 5);
  int l32 = lane & 31;
  if (n >= N) return;
  int lo = rowptr[n], hi = rowptr[n + 1];
  const uint2* embu = (const uint2*)emb;       // row = 32 uint2
  float s0 = 0.f, s1 = 0.f, s2 = 0.f, s3 = 0.f;
  for (int j = lo; j < hi; j++) {
    int src = col[j];
    uint2 v = embu[(size_t)src * 32 + l32];
    s0 += bflo(v.x); s1 += bfhi(v.x);
    s2 += bflo(v.y); s3 += bfhi(v.y);
  }
  float e1 = 1.f + epsp[l];
  uint2 hv = embu[(size_t)n * 32 + l32];
  s0 = fmaf(e1, bflo(hv.x), s0); s1 = fmaf(e1, bfhi(hv.x), s1);
  s2 = fmaf(e1, bflo(hv.y), s2); s3 = fmaf(e1, bfhi(hv.y), s3);
  uint2 o;
  o.x = ((unsigned)f2bf(s1) << 16) | (unsigned)f2bf(s0);
  o.y = ((unsigned)f2bf(s3) << 16) | (unsigned)f2bf(s2);
  ((uint2*)out)[(size_t)n * 32 + l32] = o;
}

// ---------------- GEMM: out[n][c] = cvt(sum_k in[n][k]*Wt[c][k] (+bias[c])) ----------------
// fmt 0: bf16 out (+optional per-block column partials), fmt 1: f16 out; ostride in elems
__global__ __launch_bounds__(256) void gemm_k128(
    const u16* __restrict__ in, const u16* __restrict__ Wt, const float* __restrict__ bias,
    u16* __restrict__ out, float* __restrict__ pS, float* __restrict__ pQ, int GP,
    int ostride, int fmt, int nrows) {
  __shared__ u16 Alds[64 * LDA];
  __shared__ u16 Wlds[128 * LDA];
  int tid = threadIdx.x;
  int r0 = blockIdx.x * 64;
#pragma unroll
  for (int i = 0; i < 4; i++) {
    int idx = tid + i * 256;
    int r = idx >> 4, o = idx & 15;
    uint4 v;
    if (r0 + r < nrows) v = *(const uint4*)(in + (size_t)(r0 + r) * 128 + o * 8);
    else { v.x = 0; v.y = 0; v.z = 0; v.w = 0; }
    *(uint4*)(&Alds[r * LDA + o * 8]) = v;
  }
#pragma unroll
  for (int i = 0; i < 8; i++) {
    int idx = tid + i * 256;
    int r = idx >> 4, o = idx & 15;
    uint4 v = *(const uint4*)(Wt + (size_t)r * 128 + o * 8);
    *(uint4*)(&Wlds[r * LDA + o * 8]) = v;
  }
  __syncthreads();
  int lane = tid & 63;
  int wv = tid >> 6;
  int cbase = wv * 32;
  int lr = lane & 15;
  int kg = lane >> 4;
  f32x4 acc[4][2] = {};
#pragma unroll
  for (int kc = 0; kc < 4; kc++) {
    int koff = kc * 32 + kg * 8;
    s16x8 a[4], b[2];
#pragma unroll
    for (int rt = 0; rt < 4; rt++)
      a[rt] = *reinterpret_cast<const s16x8*>(&Alds[(rt * 16 + lr) * LDA + koff]);
#pragma unroll
    for (int ct = 0; ct < 2; ct++)
      b[ct] = *reinterpret_cast<const s16x8*>(&Wlds[(cbase + ct * 16 + lr) * LDA + koff]);
#pragma unroll
    for (int rt = 0; rt < 4; rt++)
#pragma unroll
      for (int ct = 0; ct < 2; ct++)
        acc[rt][ct] = __builtin_amdgcn_mfma_f32_16x16x32_bf16(a[rt], b[ct], acc[rt][ct], 0, 0, 0);
  }
#pragma unroll
  for (int ct = 0; ct < 2; ct++) {
    int col = cbase + ct * 16 + lr;
    float bv = bias ? bias[col] : 0.f;
    float ls = 0.f, lq = 0.f;
#pragma unroll
    for (int rt = 0; rt < 4; rt++)
#pragma unroll
      for (int j = 0; j < 4; j++) {
        int row = r0 + rt * 16 + kg * 4 + j;
        if (row < nrows) {
          float v = acc[rt][ct][j] + bv;
          out[(size_t)row * ostride + col] = fmt ? f2h(v) : f2bf(v);
          ls += v; lq += v * v;
        }
      }
    if (pS) {
      ls += __shfl_xor(ls, 16); lq += __shfl_xor(lq, 16);
      ls += __shfl_xor(ls, 32); lq += __shfl_xor(lq, 32);
      if (kg == 0) {
        pS[(size_t)col * GP + blockIdx.x] = ls;
        pQ[(size_t)col * GP + blockIdx.x] = lq;
      }
    }
  }
}

// finalize BN params from per-block partials
__global__ __launch_bounds__(256) void finbn(
    const float* __restrict__ pS, const float* __restrict__ pQ, int G, int GP,
    const float* __restrict__ g, const float* __restrict__ b,
    float* __restrict__ scale, float* __restrict__ shift, float invN) {
  int c = blockIdx.x;
  int tid = threadIdx.x;
  float s = 0.f, q = 0.f;
  for (int i = tid; i < G; i += 256) {
    s += pS[(size_t)c * GP + i];
    q += pQ[(size_t)c * GP + i];
  }
  __shared__ float rs[256], rq[256];
  rs[tid] = s; rq[tid] = q;
  __syncthreads();
  for (int off = 128; off > 0; off >>= 1) {
    if (tid < off) { rs[tid] += rs[tid + off]; rq[tid] += rq[tid + off]; }
    __syncthreads();
  }
  if (tid == 0) {
    float m = rs[0] * invN;
    float v = rq[0] * invN - m * m;
    float sc = g[c] * rsqrtf(v + 1e-5f);
    scale[c] = sc;
    shift[c] = b[c] - m * sc;
  }
}

// y = bf16(relu(scale1*x+shift1)) in-place + per-block column partials of y (no atomics)
__global__ __launch_bounds__(256) void bnmid(
    u16* __restrict__ x, const float* __restrict__ scale1, const float* __restrict__ shift1,
    float* __restrict__ pS, float* __restrict__ pQ, int n4) {
  int tid = threadIdx.x;
  int i0 = blockIdx.x * 256 + tid;
  int stride = gridDim.x * 256;
  int c4 = i0 & 31;
  float sc[4], sh[4];
#pragma unroll
  for (int k = 0; k < 4; k++) {
    sc[k] = scale1[c4 * 4 + k];
    sh[k] = shift1[c4 * 4 + k];
  }
  float ls[4] = {0.f,0.f,0.f,0.f}, lq[4] = {0.f,0.f,0.f,0.f};
  for (int i = i0; i < n4; i += stride) {
    ushort4 hv = ((const ushort4*)x)[i];
    float v0 = fmaxf(fmaf(bf2f(hv.x), sc[0], sh[0]), 0.f);
    float v1 = fmaxf(fmaf(bf2f(hv.y), sc[1], sh[1]), 0.f);
    float v2 = fmaxf(fmaf(bf2f(hv.z), sc[2], sh[2]), 0.f);
    float v3 = fmaxf(fmaf(bf2f(hv.w), sc[3], sh[3]), 0.f);
    ushort4 o; o.x = f2bf(v0); o.y = f2bf(v1); o.z = f2bf(v2); o.w = f2bf(v3);
    ((ushort4*)x)[i] = o;
    ls[0] += v0; ls[1] += v1; ls[2] += v2; ls[3] += v3;
    lq[0] += v0*v0; lq[1] += v1*v1; lq[2] += v2*v2; lq[3] += v3*v3;
  }
  __shared__ float red[256][8];
#pragma unroll
  for (int k = 0; k < 4; k++) { red[tid][k] = ls[k]; red[tid][4+k] = lq[k]; }
  __syncthreads();
  for (int off = 128; off >= 32; off >>= 1) {
    if (tid < off)
#pragma unroll
      for (int s = 0; s < 8; s++) red[tid][s] += red[tid + off][s];
    __syncthreads();
  }
  if (tid < 32) {
#pragma unroll
    for (int k = 0; k < 4; k++) {
      pS[(size_t)(tid * 4 + k) * BNG + blockIdx.x] = red[tid][k];
      pQ[(size_t)(tid * 4 + k) * BNG + blockIdx.x] = red[tid][4 + k];
    }
  }
}

// out = bf16(relu(scale2*x+shift2))
__global__ void bnoutk(const u16* __restrict__ x, u16* __restrict__ out,
                       const float* __restrict__ scale2, const float* __restrict__ shift2,
                       int n4) {
  int i0 = blockIdx.x * 256 + threadIdx.x;
  int stride = gridDim.x * 256;
  int c4 = i0 & 31;
  float sc[4], sh[4];
#pragma unroll
  for (int k = 0; k < 4; k++) {
    sc[k] = scale2[c4 * 4 + k];
    sh[k] = shift2[c4 * 4 + k];
  }
  for (int i = i0; i < n4; i += stride) {
    ushort4 hv = ((const ushort4*)x)[i];
    ushort4 o;
    o.x = f2bf(fmaxf(fmaf(bf2f(hv.x), sc[0], sh[0]), 0.f));
    o.y = f2bf(fmaxf(fmaf(bf2f(hv.y), sc[1], sh[1]), 0.f));
    o.z = f2bf(fmaxf(fmaf(bf2f(hv.z), sc[2], sh[2]), 0.f));
    o.w = f2bf(fmaxf(fmaf(bf2f(hv.w), sc[3], sh[3]), 0.f));
    ((ushort4*)out)[i] = o;
  }
}

// AY[n][128..255] = AY[perm[n]][0..127]  (f16; first half = y written by GEMM)
__global__ void permk(u16* __restrict__ AY, const int* __restrict__ perm, int N) {
  int idx = blockIdx.x * 256 + threadIdx.x;
  if (idx >= N * 32) return;
  int n = idx >> 5, o = idx & 31;
  uint2* ay = (uint2*)AY;                      // row = 64 uint2
  ay[(size_t)n * 64 + 32 + o] = ay[(size_t)perm[n] * 64 + o];
}

// Afused[n] = {A_pos, A_neg} f16: mean over srcs of AY halves, fallback AY[n]
__global__ __launch_bounds__(256) void aggab(
    const u16* __restrict__ AY, u16* __restrict__ Af,
    const int* __restrict__ rowptr, const int* __restrict__ col, int N) {
  int tid = threadIdx.x;
  int wave = tid >> 6, lane = tid & 63;
  int n = blockIdx.x * 4 + wave;
  if (n >= N) return;
  int lo = rowptr[n], hi = rowptr[n + 1];
  const uint2* ay = (const uint2*)AY;          // row = 64 uint2 (512B)
  if (hi == lo) {                              // deg 0: pass-through
    ((uint2*)Af)[(size_t)n * 64 + lane] = ay[(size_t)n * 64 + lane];
    return;
  }
  float a0 = 0.f, a1 = 0.f, a2 = 0.f, a3 = 0.f;
  for (int j = lo; j < hi; j++) {
    int s = col[j];
    uint2 v = ay[(size_t)s * 64 + lane];
    float2 f0 = __half22float2(*(const __half2*)&v.x);
    float2 f1 = __half22float2(*(const __half2*)&v.y);
    a0 += f0.x; a1 += f0.y; a2 += f1.x; a3 += f1.y;
  }
  float inv = 1.f / (float)(hi - lo);
  __half2 h0 = __float22half2_rn(make_float2(a0 * inv, a1 * inv));
  __half2 h1 = __float22half2_rn(make_float2(a2 * inv, a3 * inv));
  uint2 o; o.x = *(unsigned*)&h0; o.y = *(unsigned*)&h1;
  ((uint2*)Af)[(size_t)n * 64 + lane] = o;
}

// CSR edge scoring: per dst node, B row + Wu in regs; gather Afused[src] (512B);
// packed f16 relu-dot for pos+neg; JSD accumulation
__global__ __launch_bounds__(256) void edgek(
    const u16* __restrict__ Af, const u16* __restrict__ Bf,
    const int* __restrict__ rowptr, const int* __restrict__ col,
    const u16* __restrict__ wuh, const float* __restrict__ bu,
    int N, double* __restrict__ acc) {
  int tid = threadIdx.x;
  int wave = tid >> 6, lane = tid & 63;
  int g16 = (lane >> 4), lane16 = lane & 15;
  int n = blockIdx.x * 4 + wave;
  float lp = 0.f, ln = 0.f;
  if (n < N) {
    int lo = rowptr[n], hi = rowptr[n + 1];
    uint4 bv = *(const uint4*)(Bf + (size_t)n * 128 + lane16 * 8);
    uint4 wv = *(const uint4*)(wuh + lane16 * 8);
    float bias = bu[0];
    unsigned bw[4] = {bv.x, bv.y, bv.z, bv.w};
    unsigned ww[4] = {wv.x, wv.y, wv.z, wv.w};
    for (int j = lo + g16; j < hi; j += 4) {
      int s = col[j];
      uint4 av = *(const uint4*)(Af + (size_t)s * 256 + lane16 * 8);
      uint4 nv = *(const uint4*)(Af + (size_t)s * 256 + 128 + lane16 * 8);
      unsigned aw[4] = {av.x, av.y, av.z, av.w};
      unsigned nw[4] = {nv.x, nv.y, nv.z, nv.w};
      float sp = 0.f, sn = 0.f;
#pragma unroll
      for (int i = 0; i < 4; i++) {
        sp = dot2acc(pk_add_relu(aw[i], bw[i]), ww[i], sp);
        sn = dot2acc(pk_add_relu(nw[i], bw[i]), ww[i], sn);
      }
#pragma unroll
      for (int m = 1; m < 16; m <<= 1) {
        sp += __shfl_xor(sp, m);
        sn += __shfl_xor(sn, m);
      }
      if (lane16 == 0) {
        float spos = sp + bias;
        float sneg = sn + bias;
        lp += LOG2F - softplus_neg(spos);
        ln += softplus_neg(sneg) + sneg - LOG2F;
      }
    }
  }
  __shared__ float rp[256], rn[256];
  rp[tid] = lp; rn[tid] = ln;
  __syncthreads();
  for (int off = 128; off > 0; off >>= 1) {
    if (tid < off) { rp[tid] += rp[tid + off]; rn[tid] += rn[tid + off]; }
    __syncthreads();
  }
  if (tid == 0) {
    unsafeAtomicAdd(&acc[0], (double)rp[0]);
    unsafeAtomicAdd(&acc[1], (double)rn[0]);
  }
}

__global__ void fink(const double* __restrict__ acc, float* __restrict__ out, int E) {
  out[0] = (float)((acc[1] - acc[0]) / (double)E);
}

extern "C" void kernel_launch(void* const* d_in, const int* in_sizes, int n_in,
                              void* d_out, int out_size, void* d_ws, size_t ws_size,
                              hipStream_t stream) {
  const float* features = (const float*)d_in[0];
  const float* gin_W    = (const float*)d_in[1];
  const float* gin_b    = (const float*)d_in[2];
  const float* gin_eps  = (const float*)d_in[3];
  const float* bn1_g    = (const float*)d_in[4];
  const float* bn1_b    = (const float*)d_in[5];
  const float* bn2_g    = (const float*)d_in[6];
  const float* bn2_b    = (const float*)d_in[7];
  // d_in[8]=Wz, d_in[9]=bz: dead code in reference (m1 deleted, never used)
  const float* Wlin     = (const float*)d_in[10];
  const float* blin     = (const float*)d_in[11];
  const float* Wu       = (const float*)d_in[12];
  const float* bu       = (const float*)d_in[13];
  const int* esrc       = (const int*)d_in[14];
  const int* edst       = (const int*)d_in[15];
  const int* perm       = (const int*)d_in[16];

  int N = in_sizes[0] / 128;
  int E = in_sizes[14];
  int L = in_sizes[3];
  int n4 = N * 32;
  int nb = (N + 255) / 256;
  float invN = 1.f / (float)N;
  int gemm_grid = (N + 63) / 64;

  // workspace carve-up (featb+hb aliased by Afused; aggb+h2b aliased by AY)
  char* p = (char*)d_ws;
  size_t off = 0;
  auto take = [&](size_t b) { char* r = p + off; off += (b + 255) & ~(size_t)255; return (void*)r; };
  size_t nb_h = (size_t)N * 128 * sizeof(u16);
  u16*   featb  = (u16*)take(nb_h);
  u16*   hb     = (u16*)take(nb_h);       // adjacent to featb
  u16*   aggb   = (u16*)take(nb_h);
  u16*   h2b    = (u16*)take(nb_h);       // adjacent to aggb
  u16*   Afused = featb;                  // [N][256] f16, reuses featb+hb after gemB
  u16*   AY     = aggb;                   // [N][256] f16 (y | y[perm]), reuses aggb+h2b
  u16*   Bfeat  = (u16*)take(nb_h);
  u16*   Wt     = (u16*)take((size_t)(L + 2) * 16384 * 2);
  u16*   wuh    = (u16*)take(256);
  int*   cnt    = (int*)take((size_t)N * 4);
  int*   rowptr = (int*)take((size_t)(N + 1) * 4);
  int*   cursor = (int*)take((size_t)N * 4);
  int*   col    = (int*)take((size_t)E * 4);
  int*   excl   = (int*)take((size_t)N * 4);
  int*   bsum   = (int*)take((size_t)nb * 4);
  int*   boff   = (int*)take((size_t)nb * 4);
  float* pS1    = (float*)take((size_t)128 * gemm_grid * 4);
  float* pQ1    = (float*)take((size_t)128 * gemm_grid * 4);
  float* pS2    = (float*)take((size_t)128 * BNG * 4);
  float* pQ2    = (float*)take((size_t)128 * BNG * 4);
  float* scale1 = (float*)take(512);
  float* shift1 = (float*)take(512);
  float* scale2 = (float*)take(512);
  float* shift2 = (float*)take(512);
  double* acc   = (double*)take(256);
  (void)ws_size; (void)n_in; (void)out_size;

  hipMemsetAsync(cnt, 0, (size_t)N * 4, stream);
  hipMemsetAsync(acc, 0, 16, stream);
  convw<<<((L + 2) * 16384 + 255) / 256, 256, 0, stream>>>(gin_W, Wlin, Wt, L);
  convu<<<1, 128, 0, stream>>>(Wu, wuh);
  convf<<<2048, 256, 0, stream>>>(features, featb, n4);
  // CSR build
  cntk<<<(E + 255) / 256, 256, 0, stream>>>(cnt, edst, E);
  scanA<<<nb, 256, 0, stream>>>(cnt, excl, bsum, N);
  scanB<<<1, 256, 0, stream>>>(bsum, boff, nb, rowptr + N);
  scanC<<<nb, 256, 0, stream>>>(excl, boff, rowptr, cursor, N);
  fillk<<<(E + 255) / 256, 256, 0, stream>>>(esrc, edst, cursor, col, E);
  sortk<<<(N + 255) / 256, 256, 0, stream>>>(rowptr, col, N);

  const u16* h = featb;
  for (int l = 0; l < L; l++) {
    aggk0<<<(N + 7) / 8, 256, 0, stream>>>(h, aggb, rowptr, col, gin_eps, l, N);
    gemm_k128<<<gemm_grid, 256, 0, stream>>>(aggb, Wt + (size_t)l * 16384, gin_b + l * 128,
                                             h2b, pS1, pQ1, gemm_grid, 128, 0, N);
    finbn<<<128, 256, 0, stream>>>(pS1, pQ1, gemm_grid, gemm_grid,
                                   bn1_g + l * 128, bn1_b + l * 128, scale1, shift1, invN);
    bnmid<<<BNG, 256, 0, stream>>>(h2b, scale1, shift1, pS2, pQ2, n4);
    finbn<<<128, 256, 0, stream>>>(pS2, pQ2, BNG, BNG,
                                   bn2_g + l * 128, bn2_b + l * 128, scale2, shift2, invN);
    bnoutk<<<2048, 256, 0, stream>>>(h2b, hb, scale2, shift2, n4);
    h = hb;
  }

  // y = h @ Wlin_top -> AY first half (f16); AY second half = y[perm]
  gemm_k128<<<gemm_grid, 256, 0, stream>>>(hb, Wt + (size_t)L * 16384, nullptr,
                                           AY, nullptr, nullptr, 0, 256, 1, N);
  permk<<<(N * 32 + 255) / 256, 256, 0, stream>>>(AY, perm, N);
  // B_feat = features @ Wlin_bot + blin (f16)
  gemm_k128<<<gemm_grid, 256, 0, stream>>>(featb, Wt + (size_t)(L + 1) * 16384, blin,
                                           Bfeat, nullptr, nullptr, 0, 128, 1, N);
  // A_pos/A_neg fused gather (overwrites featb/hb region)
  aggab<<<(N + 3) / 4, 256, 0, stream>>>(AY, Afused, rowptr, col, N);

  edgek<<<(N + 3) / 4, 256, 0, stream>>>(Afused, Bfeat, rowptr, col, wuh, bu, N, acc);
  fink<<<1, 1, 0, stream>>>(acc, (float*)d_out, E);
}

// Round 7
// 631.470 us; speedup vs baseline: 1.4401x; 1.4401x over previous
//
#include <hip/hip_runtime.h>
#include <hip/hip_bf16.h>
#include <hip/hip_fp16.h>

typedef float f32x4 __attribute__((ext_vector_type(4)));
typedef short s16x8 __attribute__((ext_vector_type(8)));
typedef unsigned short u16;

#define LOG2F 0.6931471805599453f
#define LDA 136   // padded LDS row stride (bf16 elems): 2-way bank alias only (free)
#define BNG 512   // bnmid grid (also its partial count)

__device__ __forceinline__ u16 f2bf(float f) {               // RNE f32->bf16
  unsigned u = __float_as_uint(f);
  u += 0x7fffu + ((u >> 16) & 1u);
  return (u16)(u >> 16);
}
__device__ __forceinline__ float bf2f(u16 h){ return __uint_as_float((unsigned)h << 16); }
__device__ __forceinline__ float bflo(unsigned u){ return __uint_as_float(u << 16); }
__device__ __forceinline__ float bfhi(unsigned u){ return __uint_as_float(u & 0xffff0000u); }
__device__ __forceinline__ u16 f2h(float f){ __half h = __float2half(f); return __half_as_ushort(h); }

// packed f16: relu(a+b) then dot2-accumulate
__device__ __forceinline__ unsigned pk_add_relu(unsigned a, unsigned b){
  unsigned t, r;
  asm("v_pk_add_f16 %0, %1, %2" : "=v"(t) : "v"(a), "v"(b));
  asm("v_pk_max_f16 %0, %1, 0" : "=v"(r) : "v"(t));
  return r;
}
__device__ __forceinline__ float dot2acc(unsigned a, unsigned w, float c){
  asm("v_dot2_f32_f16 %0, %1, %2, %0" : "+v"(c) : "v"(a), "v"(w));
  return c;
}
// fast softplus(-s) via hw exp2/log2 (v_exp_f32 = 2^x, v_log_f32 = log2 x)
__device__ __forceinline__ float softplus_neg(float s){
  float e = __builtin_amdgcn_exp2f(-fabsf(s) * 1.442695040888963f);
  return fmaxf(-s, 0.f) + __builtin_amdgcn_logf(1.f + e) * 0.6931471805599453f;
}

// ---- convert+transpose weights to bf16: Wt[m][c][k] = W_m[k][c] ----
__global__ void convw(const float* __restrict__ gW, const float* __restrict__ Wlin,
                      u16* __restrict__ Wt, int L) {
  int idx = blockIdx.x * 256 + threadIdx.x;
  int total = (L + 2) * 16384;
  if (idx >= total) return;
  int m = idx >> 14, rem = idx & 16383, c = rem >> 7, k = rem & 127;
  float v;
  if (m < L)           v = gW[(size_t)m * 16384 + k * 128 + c];
  else if (m == L)     v = Wlin[k * 128 + c];            // top half (root)
  else                 v = Wlin[(128 + k) * 128 + c];    // bottom half (features)
  Wt[idx] = f2bf(v);
}

__global__ void convu(const float* __restrict__ Wu, u16* __restrict__ wuh) {
  wuh[threadIdx.x] = f2h(Wu[threadIdx.x]);
}

__global__ void convf(const float* __restrict__ in, u16* __restrict__ out, int n4) {
  int stride = gridDim.x * blockDim.x;
  for (int i = blockIdx.x * blockDim.x + threadIdx.x; i < n4; i += stride) {
    float4 v = ((const float4*)in)[i];
    ushort4 o; o.x = f2bf(v.x); o.y = f2bf(v.y); o.z = f2bf(v.z); o.w = f2bf(v.w);
    ((ushort4*)out)[i] = o;
  }
}

// ---------------- CSR build (dst -> list of src), deterministic ----------------
__global__ void cntk(int* __restrict__ cnt, const int* __restrict__ edst, int E) {
  int e = blockIdx.x * 256 + threadIdx.x;
  if (e < E) atomicAdd(&cnt[edst[e]], 1);
}

__global__ void scanA(const int* __restrict__ cnt, int* __restrict__ excl,
                      int* __restrict__ bsum, int N) {
  __shared__ int tmp[256];
  int i = blockIdx.x * 256 + threadIdx.x;
  int v = (i < N) ? cnt[i] : 0;
  tmp[threadIdx.x] = v;
  __syncthreads();
  for (int off = 1; off < 256; off <<= 1) {
    int t = (threadIdx.x >= off) ? tmp[threadIdx.x - off] : 0;
    __syncthreads();
    tmp[threadIdx.x] += t;
    __syncthreads();
  }
  if (i < N) excl[i] = tmp[threadIdx.x] - v;
  if (threadIdx.x == 255) bsum[blockIdx.x] = tmp[255];
}

__global__ void scanB(const int* __restrict__ bsum, int* __restrict__ boff,
                      int nb, int* __restrict__ rowptrN) {
  __shared__ int tmp[256];
  __shared__ int carry;
  if (threadIdx.x == 0) carry = 0;
  __syncthreads();
  for (int base = 0; base < nb; base += 256) {
    int i = base + threadIdx.x;
    int v = (i < nb) ? bsum[i] : 0;
    tmp[threadIdx.x] = v;
    __syncthreads();
    for (int off = 1; off < 256; off <<= 1) {
      int t = (threadIdx.x >= off) ? tmp[threadIdx.x - off] : 0;
      __syncthreads();
      tmp[threadIdx.x] += t;
      __syncthreads();
    }
    if (i < nb) boff[i] = carry + tmp[threadIdx.x] - v;
    __syncthreads();
    if (threadIdx.x == 255) carry += tmp[255];
    __syncthreads();
  }
  if (threadIdx.x == 0) *rowptrN = carry;
}

__global__ void scanC(const int* __restrict__ excl, const int* __restrict__ boff,
                      int* __restrict__ rowptr, int* __restrict__ cursor, int N) {
  int i = blockIdx.x * 256 + threadIdx.x;
  if (i < N) {
    int r = excl[i] + boff[blockIdx.x];
    rowptr[i] = r; cursor[i] = r;
  }
}

__global__ void fillk(const int* __restrict__ esrc, const int* __restrict__ edst,
                      int* __restrict__ cursor, int* __restrict__ col, int E) {
  int e = blockIdx.x * 256 + threadIdx.x;
  if (e < E) {
    int pos = atomicAdd(&cursor[edst[e]], 1);
    col[pos] = esrc[e];
  }
}

// per-node insertion sort of CSR sublist -> deterministic gather order
__global__ void sortk(const int* __restrict__ rowptr, int* __restrict__ col, int N) {
  int n = blockIdx.x * 256 + threadIdx.x;
  if (n >= N) return;
  int lo = rowptr[n], hi = rowptr[n + 1];
  for (int i = lo + 1; i < hi; i++) {
    int v = col[i];
    int j = i - 1;
    while (j >= lo && col[j] > v) { col[j + 1] = col[j]; j--; }
    col[j + 1] = v;
  }
}

// dstj[j] = n for j in [rowptr[n], rowptr[n+1])  (CSR-expanded dst ids)
__global__ void dstk(const int* __restrict__ rowptr, int* __restrict__ dstj, int N) {
  int n = blockIdx.x * 256 + threadIdx.x;
  if (n >= N) return;
  int lo = rowptr[n], hi = rowptr[n + 1];
  for (int j = lo; j < hi; j++) dstj[j] = n;
}

// ---------------- GIN aggregation: out[n] = bf16((1+eps)*emb[n] + sum_src emb[src]) ----
// 4 nodes per wave: 16-lane groups, uint4 (8 bf16) per lane
__global__ __launch_bounds__(256) void aggk0(
    const u16* __restrict__ emb, u16* __restrict__ out,
    const int* __restrict__ rowptr, const int* __restrict__ col,
    const float* __restrict__ epsp, int l, int N) {
  int tid = threadIdx.x;
  int grp = tid >> 4, lane16 = tid & 15;
  int n = blockIdx.x * 16 + grp;
  if (n >= N) return;
  int lo = rowptr[n], hi = rowptr[n + 1];
  const uint4* embu = (const uint4*)emb;       // row = 16 uint4
  float s[8] = {0.f,0.f,0.f,0.f,0.f,0.f,0.f,0.f};
  for (int j = lo; j < hi; j++) {
    int src = col[j];
    uint4 v = embu[(size_t)src * 16 + lane16];
    s[0] += bflo(v.x); s[1] += bfhi(v.x);
    s[2] += bflo(v.y); s[3] += bfhi(v.y);
    s[4] += bflo(v.z); s[5] += bfhi(v.z);
    s[6] += bflo(v.w); s[7] += bfhi(v.w);
  }
  float e1 = 1.f + epsp[l];
  uint4 hv = embu[(size_t)n * 16 + lane16];
  s[0] = fmaf(e1, bflo(hv.x), s[0]); s[1] = fmaf(e1, bfhi(hv.x), s[1]);
  s[2] = fmaf(e1, bflo(hv.y), s[2]); s[3] = fmaf(e1, bfhi(hv.y), s[3]);
  s[4] = fmaf(e1, bflo(hv.z), s[4]); s[5] = fmaf(e1, bfhi(hv.z), s[5]);
  s[6] = fmaf(e1, bflo(hv.w), s[6]); s[7] = fmaf(e1, bfhi(hv.w), s[7]);
  uint4 o;
  o.x = ((unsigned)f2bf(s[1]) << 16) | (unsigned)f2bf(s[0]);
  o.y = ((unsigned)f2bf(s[3]) << 16) | (unsigned)f2bf(s[2]);
  o.z = ((unsigned)f2bf(s[5]) << 16) | (unsigned)f2bf(s[4]);
  o.w = ((unsigned)f2bf(s[7]) << 16) | (unsigned)f2bf(s[6]);
  ((uint4*)out)[(size_t)n * 16 + lane16] = o;
}

// ---------------- GEMM: out[n][c] = cvt(sum_k in[n][k]*Wt[c][k] (+bias[c])) ----------------
__global__ __launch_bounds__(256) void gemm_k128(
    const u16* __restrict__ in, const u16* __restrict__ Wt, const float* __restrict__ bias,
    u16* __restrict__ out, float* __restrict__ pS, float* __restrict__ pQ, int GP,
    int ostride, int fmt, int nrows) {
  __shared__ u16 Alds[64 * LDA];
  __shared__ u16 Wlds[128 * LDA];
  int tid = threadIdx.x;
  int r0 = blockIdx.x * 64;
#pragma unroll
  for (int i = 0; i < 4; i++) {
    int idx = tid + i * 256;
    int r = idx >> 4, o = idx & 15;
    uint4 v;
    if (r0 + r < nrows) v = *(const uint4*)(in + (size_t)(r0 + r) * 128 + o * 8);
    else { v.x = 0; v.y = 0; v.z = 0; v.w = 0; }
    *(uint4*)(&Alds[r * LDA + o * 8]) = v;
  }
#pragma unroll
  for (int i = 0; i < 8; i++) {
    int idx = tid + i * 256;
    int r = idx >> 4, o = idx & 15;
    uint4 v = *(const uint4*)(Wt + (size_t)r * 128 + o * 8);
    *(uint4*)(&Wlds[r * LDA + o * 8]) = v;
  }
  __syncthreads();
  int lane = tid & 63;
  int wv = tid >> 6;
  int cbase = wv * 32;
  int lr = lane & 15;
  int kg = lane >> 4;
  f32x4 acc[4][2] = {};
#pragma unroll
  for (int kc = 0; kc < 4; kc++) {
    int koff = kc * 32 + kg * 8;
    s16x8 a[4], b[2];
#pragma unroll
    for (int rt = 0; rt < 4; rt++)
      a[rt] = *reinterpret_cast<const s16x8*>(&Alds[(rt * 16 + lr) * LDA + koff]);
#pragma unroll
    for (int ct = 0; ct < 2; ct++)
      b[ct] = *reinterpret_cast<const s16x8*>(&Wlds[(cbase + ct * 16 + lr) * LDA + koff]);
#pragma unroll
    for (int rt = 0; rt < 4; rt++)
#pragma unroll
      for (int ct = 0; ct < 2; ct++)
        acc[rt][ct] = __builtin_amdgcn_mfma_f32_16x16x32_bf16(a[rt], b[ct], acc[rt][ct], 0, 0, 0);
  }
#pragma unroll
  for (int ct = 0; ct < 2; ct++) {
    int col = cbase + ct * 16 + lr;
    float bv = bias ? bias[col] : 0.f;
    float ls = 0.f, lq = 0.f;
#pragma unroll
    for (int rt = 0; rt < 4; rt++)
#pragma unroll
      for (int j = 0; j < 4; j++) {
        int row = r0 + rt * 16 + kg * 4 + j;
        if (row < nrows) {
          float v = acc[rt][ct][j] + bv;
          out[(size_t)row * ostride + col] = fmt ? f2h(v) : f2bf(v);
          ls += v; lq += v * v;
        }
      }
    if (pS) {
      ls += __shfl_xor(ls, 16); lq += __shfl_xor(lq, 16);
      ls += __shfl_xor(ls, 32); lq += __shfl_xor(lq, 32);
      if (kg == 0) {
        pS[(size_t)col * GP + blockIdx.x] = ls;
        pQ[(size_t)col * GP + blockIdx.x] = lq;
      }
    }
  }
}

// finalize BN params from per-block partials
__global__ __launch_bounds__(256) void finbn(
    const float* __restrict__ pS, const float* __restrict__ pQ, int G, int GP,
    const float* __restrict__ g, const float* __restrict__ b,
    float* __restrict__ scale, float* __restrict__ shift, float invN) {
  int c = blockIdx.x;
  int tid = threadIdx.x;
  float s = 0.f, q = 0.f;
  for (int i = tid; i < G; i += 256) {
    s += pS[(size_t)c * GP + i];
    q += pQ[(size_t)c * GP + i];
  }
  __shared__ float rs[256], rq[256];
  rs[tid] = s; rq[tid] = q;
  __syncthreads();
  for (int off = 128; off > 0; off >>= 1) {
    if (tid < off) { rs[tid] += rs[tid + off]; rq[tid] += rq[tid + off]; }
    __syncthreads();
  }
  if (tid == 0) {
    float m = rs[0] * invN;
    float v = rq[0] * invN - m * m;
    float sc = g[c] * rsqrtf(v + 1e-5f);
    scale[c] = sc;
    shift[c] = b[c] - m * sc;
  }
}

// y = bf16(relu(scale1*x+shift1)) in-place + per-block column partials of y
__global__ __launch_bounds__(256) void bnmid(
    u16* __restrict__ x, const float* __restrict__ scale1, const float* __restrict__ shift1,
    float* __restrict__ pS, float* __restrict__ pQ, int n4) {
  int tid = threadIdx.x;
  int i0 = blockIdx.x * 256 + tid;
  int stride = gridDim.x * 256;
  int c4 = i0 & 31;
  float sc[4], sh[4];
#pragma unroll
  for (int k = 0; k < 4; k++) {
    sc[k] = scale1[c4 * 4 + k];
    sh[k] = shift1[c4 * 4 + k];
  }
  float ls[4] = {0.f,0.f,0.f,0.f}, lq[4] = {0.f,0.f,0.f,0.f};
  for (int i = i0; i < n4; i += stride) {
    ushort4 hv = ((const ushort4*)x)[i];
    float v0 = fmaxf(fmaf(bf2f(hv.x), sc[0], sh[0]), 0.f);
    float v1 = fmaxf(fmaf(bf2f(hv.y), sc[1], sh[1]), 0.f);
    float v2 = fmaxf(fmaf(bf2f(hv.z), sc[2], sh[2]), 0.f);
    float v3 = fmaxf(fmaf(bf2f(hv.w), sc[3], sh[3]), 0.f);
    ushort4 o; o.x = f2bf(v0); o.y = f2bf(v1); o.z = f2bf(v2); o.w = f2bf(v3);
    ((ushort4*)x)[i] = o;
    ls[0] += v0; ls[1] += v1; ls[2] += v2; ls[3] += v3;
    lq[0] += v0*v0; lq[1] += v1*v1; lq[2] += v2*v2; lq[3] += v3*v3;
  }
  __shared__ float red[256][8];
#pragma unroll
  for (int k = 0; k < 4; k++) { red[tid][k] = ls[k]; red[tid][4+k] = lq[k]; }
  __syncthreads();
  for (int off = 128; off >= 32; off >>= 1) {
    if (tid < off)
#pragma unroll
      for (int s = 0; s < 8; s++) red[tid][s] += red[tid + off][s];
    __syncthreads();
  }
  if (tid < 32) {
#pragma unroll
    for (int k = 0; k < 4; k++) {
      pS[(size_t)(tid * 4 + k) * BNG + blockIdx.x] = red[tid][k];
      pQ[(size_t)(tid * 4 + k) * BNG + blockIdx.x] = red[tid][4 + k];
    }
  }
}

// out = bf16(relu(scale2*x+shift2))
__global__ void bnoutk(const u16* __restrict__ x, u16* __restrict__ out,
                       const float* __restrict__ scale2, const float* __restrict__ shift2,
                       int n4) {
  int i0 = blockIdx.x * 256 + threadIdx.x;
  int stride = gridDim.x * 256;
  int c4 = i0 & 31;
  float sc[4], sh[4];
#pragma unroll
  for (int k = 0; k < 4; k++) {
    sc[k] = scale2[c4 * 4 + k];
    sh[k] = shift2[c4 * 4 + k];
  }
  for (int i = i0; i < n4; i += stride) {
    ushort4 hv = ((const ushort4*)x)[i];
    ushort4 o;
    o.x = f2bf(fmaxf(fmaf(bf2f(hv.x), sc[0], sh[0]), 0.f));
    o.y = f2bf(fmaxf(fmaf(bf2f(hv.y), sc[1], sh[1]), 0.f));
    o.z = f2bf(fmaxf(fmaf(bf2f(hv.z), sc[2], sh[2]), 0.f));
    o.w = f2bf(fmaxf(fmaf(bf2f(hv.w), sc[3], sh[3]), 0.f));
    ((ushort4*)out)[i] = o;
  }
}

// AY[n][128..255] = AY[perm[n]][0..127]  (f16; first half = y written by GEMM)
__global__ void permk(u16* __restrict__ AY, const int* __restrict__ perm, int N) {
  int idx = blockIdx.x * 256 + threadIdx.x;
  if (idx >= N * 32) return;
  int n = idx >> 5, o = idx & 31;
  uint2* ay = (uint2*)AY;                      // row = 64 uint2
  ay[(size_t)n * 64 + 32 + o] = ay[(size_t)perm[n] * 64 + o];
}

// Afused[n] = {A_pos, A_neg} f16: mean over srcs of AY halves, fallback AY[n]
// 2 nodes per wave: 32-lane groups, uint4 per lane (row = 512 B)
__global__ __launch_bounds__(256) void aggab(
    const u16* __restrict__ AY, u16* __restrict__ Af,
    const int* __restrict__ rowptr, const int* __restrict__ col, int N) {
  int tid = threadIdx.x;
  int grp = tid >> 5, l32 = tid & 31;
  int n = blockIdx.x * 8 + grp;
  if (n >= N) return;
  int lo = rowptr[n], hi = rowptr[n + 1];
  const uint4* ay = (const uint4*)AY;          // row = 32 uint4
  if (hi == lo) {                              // deg 0: pass-through
    ((uint4*)Af)[(size_t)n * 32 + l32] = ay[(size_t)n * 32 + l32];
    return;
  }
  float a[8] = {0.f,0.f,0.f,0.f,0.f,0.f,0.f,0.f};
  for (int j = lo; j < hi; j++) {
    int s = col[j];
    uint4 v = ay[(size_t)s * 32 + l32];
    float2 f0 = __half22float2(*(const __half2*)&v.x);
    float2 f1 = __half22float2(*(const __half2*)&v.y);
    float2 f2 = __half22float2(*(const __half2*)&v.z);
    float2 f3 = __half22float2(*(const __half2*)&v.w);
    a[0] += f0.x; a[1] += f0.y; a[2] += f1.x; a[3] += f1.y;
    a[4] += f2.x; a[5] += f2.y; a[6] += f3.x; a[7] += f3.y;
  }
  float inv = 1.f / (float)(hi - lo);
  __half2 h0 = __float22half2_rn(make_float2(a[0] * inv, a[1] * inv));
  __half2 h1 = __float22half2_rn(make_float2(a[2] * inv, a[3] * inv));
  __half2 h2 = __float22half2_rn(make_float2(a[4] * inv, a[5] * inv));
  __half2 h3 = __float22half2_rn(make_float2(a[6] * inv, a[7] * inv));
  uint4 o;
  o.x = *(unsigned*)&h0; o.y = *(unsigned*)&h1;
  o.z = *(unsigned*)&h2; o.w = *(unsigned*)&h3;
  ((uint4*)Af)[(size_t)n * 32 + l32] = o;
}

// flat CSR-ordered edge scoring: 16 lanes/edge, contiguous chunk per group
// (B[dst] repeats within a chunk -> L1-hot; Af[src] is the random stream)
__global__ __launch_bounds__(256) void edgek(
    const u16* __restrict__ Af, const u16* __restrict__ Bf,
    const int* __restrict__ col, const int* __restrict__ dstj,
    const u16* __restrict__ wuh, const float* __restrict__ bu,
    int E, double* __restrict__ acc) {
  int tid = threadIdx.x;
  int lane16 = tid & 15;
  uint4 wv = *(const uint4*)(wuh + lane16 * 8);
  unsigned ww[4] = {wv.x, wv.y, wv.z, wv.w};
  float bias = bu[0];
  float lp = 0.f, ln = 0.f;
  int g = (blockIdx.x * 256 + tid) >> 4;
  int ng = (gridDim.x * 256) >> 4;
  int per = (E + ng - 1) / ng;
  int j0 = g * per;
  int j1 = min(E, j0 + per);
  for (int j = j0; j < j1; j++) {
    int s = col[j];
    int d = dstj[j];
    uint4 av = *(const uint4*)(Af + (size_t)s * 256 + lane16 * 8);
    uint4 nv = *(const uint4*)(Af + (size_t)s * 256 + 128 + lane16 * 8);
    uint4 bv = *(const uint4*)(Bf + (size_t)d * 128 + lane16 * 8);
    unsigned aw[4] = {av.x, av.y, av.z, av.w};
    unsigned nw[4] = {nv.x, nv.y, nv.z, nv.w};
    unsigned bw[4] = {bv.x, bv.y, bv.z, bv.w};
    float sp = 0.f, sn = 0.f;
#pragma unroll
    for (int i = 0; i < 4; i++) {
      sp = dot2acc(pk_add_relu(aw[i], bw[i]), ww[i], sp);
      sn = dot2acc(pk_add_relu(nw[i], bw[i]), ww[i], sn);
    }
#pragma unroll
    for (int m = 1; m < 16; m <<= 1) {
      sp += __shfl_xor(sp, m);
      sn += __shfl_xor(sn, m);
    }
    if (lane16 == 0) {
      float spos = sp + bias;
      float sneg = sn + bias;
      lp += LOG2F - softplus_neg(spos);
      ln += softplus_neg(sneg) + sneg - LOG2F;
    }
  }
  __shared__ float rp[256], rn[256];
  rp[tid] = lp; rn[tid] = ln;
  __syncthreads();
  for (int off = 128; off > 0; off >>= 1) {
    if (tid < off) { rp[tid] += rp[tid + off]; rn[tid] += rn[tid + off]; }
    __syncthreads();
  }
  if (tid == 0) {
    unsafeAtomicAdd(&acc[0], (double)rp[0]);
    unsafeAtomicAdd(&acc[1], (double)rn[0]);
  }
}

__global__ void fink(const double* __restrict__ acc, float* __restrict__ out, int E) {
  out[0] = (float)((acc[1] - acc[0]) / (double)E);
}

extern "C" void kernel_launch(void* const* d_in, const int* in_sizes, int n_in,
                              void* d_out, int out_size, void* d_ws, size_t ws_size,
                              hipStream_t stream) {
  const float* features = (const float*)d_in[0];
  const float* gin_W    = (const float*)d_in[1];
  const float* gin_b    = (const float*)d_in[2];
  const float* gin_eps  = (const float*)d_in[3];
  const float* bn1_g    = (const float*)d_in[4];
  const float* bn1_b    = (const float*)d_in[5];
  const float* bn2_g    = (const float*)d_in[6];
  const float* bn2_b    = (const float*)d_in[7];
  // d_in[8]=Wz, d_in[9]=bz: dead code in reference (m1 deleted, never used)
  const float* Wlin     = (const float*)d_in[10];
  const float* blin     = (const float*)d_in[11];
  const float* Wu       = (const float*)d_in[12];
  const float* bu       = (const float*)d_in[13];
  const int* esrc       = (const int*)d_in[14];
  const int* edst       = (const int*)d_in[15];
  const int* perm       = (const int*)d_in[16];

  int N = in_sizes[0] / 128;
  int E = in_sizes[14];
  int L = in_sizes[3];
  int n4 = N * 32;
  int nb = (N + 255) / 256;
  float invN = 1.f / (float)N;
  int gemm_grid = (N + 63) / 64;

  // workspace carve-up (featb+hb aliased by Afused; aggb+h2b aliased by AY)
  char* p = (char*)d_ws;
  size_t off = 0;
  auto take = [&](size_t b) { char* r = p + off; off += (b + 255) & ~(size_t)255; return (void*)r; };
  size_t nb_h = (size_t)N * 128 * sizeof(u16);
  u16*   featb  = (u16*)take(nb_h);
  u16*   hb     = (u16*)take(nb_h);       // adjacent to featb
  u16*   aggb   = (u16*)take(nb_h);
  u16*   h2b    = (u16*)take(nb_h);       // adjacent to aggb
  u16*   Afused = featb;                  // [N][256] f16, reuses featb+hb after gemB
  u16*   AY     = aggb;                   // [N][256] f16 (y | y[perm]), reuses aggb+h2b
  u16*   Bfeat  = (u16*)take(nb_h);
  u16*   Wt     = (u16*)take((size_t)(L + 2) * 16384 * 2);
  u16*   wuh    = (u16*)take(256);
  int*   cnt    = (int*)take((size_t)N * 4);
  int*   rowptr = (int*)take((size_t)(N + 1) * 4);
  int*   cursor = (int*)take((size_t)N * 4);
  int*   col    = (int*)take((size_t)E * 4);
  int*   dstj   = (int*)take((size_t)E * 4);
  int*   excl   = (int*)take((size_t)N * 4);
  int*   bsum   = (int*)take((size_t)nb * 4);
  int*   boff   = (int*)take((size_t)nb * 4);
  float* pS1    = (float*)take((size_t)128 * gemm_grid * 4);
  float* pQ1    = (float*)take((size_t)128 * gemm_grid * 4);
  float* pS2    = (float*)take((size_t)128 * BNG * 4);
  float* pQ2    = (float*)take((size_t)128 * BNG * 4);
  float* scale1 = (float*)take(512);
  float* shift1 = (float*)take(512);
  float* scale2 = (float*)take(512);
  float* shift2 = (float*)take(512);
  double* acc   = (double*)take(256);
  (void)ws_size; (void)n_in; (void)out_size;

  hipMemsetAsync(cnt, 0, (size_t)N * 4, stream);
  hipMemsetAsync(acc, 0, 16, stream);
  convw<<<((L + 2) * 16384 + 255) / 256, 256, 0, stream>>>(gin_W, Wlin, Wt, L);
  convu<<<1, 128, 0, stream>>>(Wu, wuh);
  convf<<<2048, 256, 0, stream>>>(features, featb, n4);
  // CSR build
  cntk<<<(E + 255) / 256, 256, 0, stream>>>(cnt, edst, E);
  scanA<<<nb, 256, 0, stream>>>(cnt, excl, bsum, N);
  scanB<<<1, 256, 0, stream>>>(bsum, boff, nb, rowptr + N);
  scanC<<<nb, 256, 0, stream>>>(excl, boff, rowptr, cursor, N);
  fillk<<<(E + 255) / 256, 256, 0, stream>>>(esrc, edst, cursor, col, E);
  sortk<<<(N + 255) / 256, 256, 0, stream>>>(rowptr, col, N);
  dstk<<<(N + 255) / 256, 256, 0, stream>>>(rowptr, dstj, N);

  const u16* h = featb;
  for (int l = 0; l < L; l++) {
    aggk0<<<(N + 15) / 16, 256, 0, stream>>>(h, aggb, rowptr, col, gin_eps, l, N);
    gemm_k128<<<gemm_grid, 256, 0, stream>>>(aggb, Wt + (size_t)l * 16384, gin_b + l * 128,
                                             h2b, pS1, pQ1, gemm_grid, 128, 0, N);
    finbn<<<128, 256, 0, stream>>>(pS1, pQ1, gemm_grid, gemm_grid,
                                   bn1_g + l * 128, bn1_b + l * 128, scale1, shift1, invN);
    bnmid<<<BNG, 256, 0, stream>>>(h2b, scale1, shift1, pS2, pQ2, n4);
    finbn<<<128, 256, 0, stream>>>(pS2, pQ2, BNG, BNG,
                                   bn2_g + l * 128, bn2_b + l * 128, scale2, shift2, invN);
    bnoutk<<<2048, 256, 0, stream>>>(h2b, hb, scale2, shift2, n4);
    h = hb;
  }

  // y = h @ Wlin_top -> AY first half (f16); AY second half = y[perm]
  gemm_k128<<<gemm_grid, 256, 0, stream>>>(hb, Wt + (size_t)L * 16384, nullptr,
                                           AY, nullptr, nullptr, 0, 256, 1, N);
  permk<<<(N * 32 + 255) / 256, 256, 0, stream>>>(AY, perm, N);
  // B_feat = features @ Wlin_bot + blin (f16)
  gemm_k128<<<gemm_grid, 256, 0, stream>>>(featb, Wt + (size_t)(L + 1) * 16384, blin,
                                           Bfeat, nullptr, nullptr, 0, 128, 1, N);
  // A_pos/A_neg fused gather (overwrites featb/hb region)
  aggab<<<(N + 7) / 8, 256, 0, stream>>>(AY, Afused, rowptr, col, N);

  edgek<<<2048, 256, 0, stream>>>(Afused, Bfeat, col, dstj, wuh, bu, E, acc);
  fink<<<1, 1, 0, stream>>>(acc, (float*)d_out, E);
}